// Round 12
// baseline (172.839 us; speedup 1.0000x reference)
//
#include <hip/hip_runtime.h>
#include <stdint.h>

// Problem constants (from reference)
#define NNODES 50000
#define NEDGES 1000000
#define DIM    64
#define NREL   8
#define NBUCK  391          // ceil(50000/128); bucket = dst >> 7 (128-node range)
#define BCAP   2944         // per-bucket staging capacity (expected ~2558, +7.6 sigma)
#define NBLK   3125         // 50000 / 16 output blocks
#define RCAP   480          // per-16-node record capacity (expected ~320, +8.9 sigma)
#define APITCH 584          // LDS bf16 tile pitch (576 + 8)

typedef __attribute__((ext_vector_type(8))) short short8;
typedef __attribute__((ext_vector_type(4))) float float4v;
typedef __attribute__((ext_vector_type(4))) unsigned short us4;

__device__ __forceinline__ float bf2f(unsigned short u) {
  return __uint_as_float(((unsigned int)u) << 16);
}
__device__ __forceinline__ unsigned short f2bf(float f) {
  unsigned int u = __float_as_uint(f);
  unsigned int r = (u + 0x7FFF + ((u >> 16) & 1)) >> 16;   // round-nearest-even
  return (unsigned short)r;
}

#define CASTBLK ((NNODES * DIM / 4 + 255) / 256)
#define PREPBLK ((18 * 4 * 64 * 8 + 255) / 256)

// K0: fused prep (B fragments + bias) and x f32->bf16 cast; zero bucket_cursor.
__global__ void prep_cast_kernel(const float* __restrict__ Wlin,
                                 const float* __restrict__ Wself,
                                 const float* __restrict__ blin,
                                 const float* __restrict__ bself,
                                 const float4* __restrict__ x4,
                                 unsigned short* __restrict__ Bf2,
                                 float* __restrict__ bsum,
                                 us4* __restrict__ xb,
                                 int* __restrict__ bucket_cursor) {
  int gt = blockIdx.x * 256 + threadIdx.x;
  if (gt < NBUCK) bucket_cursor[gt] = 0;
  if (gt < 64) bsum[gt] = blin[gt] + bself[gt];
  if (blockIdx.x < CASTBLK) {
    int t = gt;
    if (t < NNODES * DIM / 4) {
      float4 v = x4[t];
      us4 o;
      o.x = f2bf(v.x); o.y = f2bf(v.y); o.z = f2bf(v.z); o.w = f2bf(v.w);
      xb[t] = o;
    }
  } else {
    int t = (blockIdx.x - CASTBLK) * 256 + threadIdx.x;
    if (t < 18 * 4 * 64 * 8) {
      int j  = t & 7;
      int l  = (t >> 3) & 63;
      int ct = (t >> 9) & 3;
      int ks = t >> 11;
      int k = ks * 32 + (l >> 4) * 8 + j;
      int c = ct * 16 + (l & 15);
      float v = (k < 512) ? Wlin[(size_t)k * 64 + c] : Wself[(size_t)(k - 512) * 64 + c];
      Bf2[t] = f2bf(v);
    }
  }
}

// K1: binned scatter with block-local LDS counting sort + coalesced run flush.
// Record: x = src(16) | rel(3)<<16 | dst_low7(7)<<19, y = w bits.
__global__ __launch_bounds__(1024) void binscatter_kernel(
    const int4* __restrict__ src4, const int4* __restrict__ dst4,
    const int4* __restrict__ rel4, const float4* __restrict__ w4,
    int* __restrict__ bucket_cursor, uint2* __restrict__ staged, int E4) {
  __shared__ int lhist[NBUCK];
  __shared__ int lscan[NBUCK];
  __shared__ int lbaseg[NBUCK];
  __shared__ uint2 lrec[4096];              // 32 KB
  __shared__ unsigned short lbuck[4096];    // 8 KB
  int tid = threadIdx.x;
  if (tid < NBUCK) lhist[tid] = 0;
  __syncthreads();
  int t = blockIdx.x * 1024 + tid;
  bool valid = t < E4;
  int4 s = {0,0,0,0}, d = {0,0,0,0}, r = {0,0,0,0};
  float4 w = {0.f,0.f,0.f,0.f};
  if (valid) { s = src4[t]; d = dst4[t]; r = rel4[t]; w = w4[t]; }
  int b0=0,b1=0,b2=0,b3=0,p0=0,p1=0,p2=0,p3=0;
  if (valid) {
    b0 = d.x >> 7; p0 = atomicAdd(&lhist[b0], 1);
    b1 = d.y >> 7; p1 = atomicAdd(&lhist[b1], 1);
    b2 = d.z >> 7; p2 = atomicAdd(&lhist[b2], 1);
    b3 = d.w >> 7; p3 = atomicAdd(&lhist[b3], 1);
  }
  __syncthreads();
  if (tid < 64) {                 // wave 0: exclusive scan of 391 counts
    int carry = 0;
    #pragma unroll
    for (int c = 0; c < 7; c++) {
      int i = c * 64 + tid;
      int v = (i < NBUCK) ? lhist[i] : 0;
      int inc = v;
      #pragma unroll
      for (int dd = 1; dd < 64; dd <<= 1) {
        int tt = __shfl_up(inc, dd);
        if (tid >= dd) inc += tt;
      }
      if (i < NBUCK) lscan[i] = carry + inc - v;
      carry += __shfl(inc, 63);
    }
  }
  __syncthreads();
  if (valid) {
    int q;
    q = lscan[b0] + p0; lrec[q] = make_uint2((unsigned)s.x | ((unsigned)r.x << 16) | ((unsigned)(d.x & 127) << 19), __float_as_uint(w.x)); lbuck[q] = (unsigned short)b0;
    q = lscan[b1] + p1; lrec[q] = make_uint2((unsigned)s.y | ((unsigned)r.y << 16) | ((unsigned)(d.y & 127) << 19), __float_as_uint(w.y)); lbuck[q] = (unsigned short)b1;
    q = lscan[b2] + p2; lrec[q] = make_uint2((unsigned)s.z | ((unsigned)r.z << 16) | ((unsigned)(d.z & 127) << 19), __float_as_uint(w.z)); lbuck[q] = (unsigned short)b2;
    q = lscan[b3] + p3; lrec[q] = make_uint2((unsigned)s.w | ((unsigned)r.w << 16) | ((unsigned)(d.w & 127) << 19), __float_as_uint(w.w)); lbuck[q] = (unsigned short)b3;
  }
  if (tid < NBUCK && lhist[tid] > 0)
    lbaseg[tid] = atomicAdd(&bucket_cursor[tid], lhist[tid]);
  __syncthreads();
  int cntblk = NEDGES - blockIdx.x * 4096;
  if (cntblk > 4096) cntblk = 4096;
  for (int i = tid; i < cntblk; i += 1024) {     // linear LDS read, run-coalesced store
    int b = lbuck[i];
    int idx = lbaseg[b] + (i - lscan[b]);
    if (idx < BCAP) staged[(size_t)b * BCAP + idx] = lrec[i];
  }
}

// K2: FUSED filter + sort + degree + aggregate + output GEMM. Block = 16 nodes,
// 512 threads = 8 waves. Steps: (1) scan the 128-node bucket's records,
// ballot-compact the ones for our 16 nodes into LDS; (2) LDS counting sort by
// 128 (row,rel) keys; (3) per wave x 2 nodes: per-rel segment deg sum -> inv,
// then the validated gather engine (uniform LDS meta -> broadcast -> 1 fmac/edge);
// (4) MFMA epilogue on waves 0-3.
__global__ __launch_bounds__(512) void fused_kernel(const int* __restrict__ bucket_cursor,
                                                    const uint2* __restrict__ staged,
                                                    const unsigned short* __restrict__ xb,
                                                    const unsigned short* __restrict__ Bf2,
                                                    const float* __restrict__ bsum,
                                                    float* __restrict__ out) {
  __shared__ uint2 recs[RCAP];           // 3.75 KB raw compacted
  __shared__ uint2 srecs[RCAP];          // 3.75 KB sorted
  __shared__ int   hist[128];
  __shared__ int   cur[128];
  __shared__ int   segs[129];
  __shared__ int   cnt_s;
  __shared__ unsigned short At[16 * APITCH];   // 18.25 KB
  int tid  = threadIdx.x;
  int wave = tid >> 6;
  int lane = tid & 63;
  int g = blockIdx.x;
  int b = g >> 3, sub = g & 7;
  int nodeBase = g * 16;
  const char* xbb = (const char*)xb;
  int lane2 = lane * 2;

  if (tid < 128) hist[tid] = 0;
  if (tid == 0) cnt_s = 0;
  __syncthreads();

  int cnt = bucket_cursor[b];
  if (cnt > BCAP) cnt = BCAP;
  const uint2* sb = staged + (size_t)b * BCAP;

  // (1) ballot-compact records for rows [sub*16, sub*16+16)
  for (int i0 = 0; i0 < cnt; i0 += 512) {
    int i = i0 + tid;
    uint2 rec = make_uint2(0u, 0u);
    bool match = false;
    if (i < cnt) {
      rec = sb[i];
      match = (int)((rec.x >> 23) & 7) == sub;   // row7>>4 == sub
    }
    unsigned long long mask = __ballot(match);
    int wcnt = __popcll(mask);
    int prefix = __popcll(mask & ((1ull << lane) - 1ull));
    int wbase = 0;
    if (lane == 0 && wcnt > 0) wbase = atomicAdd(&cnt_s, wcnt);
    wbase = __shfl(wbase, 0);
    if (match) {
      int p = wbase + prefix;
      if (p < RCAP) {
        recs[p] = rec;
        int key = (((rec.x >> 19) & 15) << 3) | ((rec.x >> 16) & 7);
        atomicAdd(&hist[key], 1);
      }
    }
  }
  __syncthreads();
  int cnt16 = cnt_s; if (cnt16 > RCAP) cnt16 = RCAP;

  // (2a) scan 128 keys (wave 0, 2 chunks of 64)
  if (tid < 64) {
    int carry = 0;
    #pragma unroll
    for (int c = 0; c < 2; c++) {
      int v = hist[c * 64 + tid];
      int inc = v;
      #pragma unroll
      for (int d = 1; d < 64; d <<= 1) {
        int tt = __shfl_up(inc, d);
        if (tid >= d) inc += tt;
      }
      segs[c * 64 + tid] = carry + inc - v;
      cur[c * 64 + tid]  = carry + inc - v;
      carry += __shfl(inc, 63);
    }
    if (tid == 0) segs[128] = carry;
  }
  __syncthreads();
  // (2b) scatter into sorted order
  for (int i = tid; i < cnt16; i += 512) {
    uint2 rec = recs[i];
    int key = (((rec.x >> 19) & 15) << 3) | ((rec.x >> 16) & 7);
    int p = atomicAdd(&cur[key], 1);
    srecs[p] = rec;
  }
  __syncthreads();

  // (3) aggregate: each wave handles 2 nodes
  #pragma unroll
  for (int i = 0; i < 2; i++) {
    int row  = wave * 2 + i;
    int node = nodeBase + row;
    float acc[8];
    #pragma unroll
    for (int r = 0; r < 8; r++) {
      int e  = segs[row * 8 + r];
      int e1 = segs[row * 8 + r + 1];
      // pass 1: degree (weight sum) for this (node,rel)
      float dsum = 0.f;
      for (int t2 = e; t2 < e1; t2++) dsum += __uint_as_float(srecs[t2].y);
      float inv = (dsum != 0.f) ? (1.0f / dsum) : 0.f;
      // pass 2: gather-accumulate, 1 fmac/edge, unroll 2
      float a = 0.f;
      for (; e + 2 <= e1; e += 2) {
        uint2 m0 = srecs[e];
        uint2 m1 = srecs[e + 1];
        unsigned o0 = (m0.x & 0xFFFFu) << 7;
        unsigned o1 = (m1.x & 0xFFFFu) << 7;
        float v0 = bf2f(*(const unsigned short*)(xbb + o0 + lane2));
        float v1 = bf2f(*(const unsigned short*)(xbb + o1 + lane2));
        a += (__uint_as_float(m0.y) * inv) * v0;
        a += (__uint_as_float(m1.y) * inv) * v1;
      }
      if (e < e1) {
        uint2 m0 = srecs[e];
        unsigned o0 = (m0.x & 0xFFFFu) << 7;
        a += (__uint_as_float(m0.y) * inv) * bf2f(*(const unsigned short*)(xbb + o0 + lane2));
      }
      acc[r] = a;
    }
    unsigned short* ar = At + row * APITCH;
    #pragma unroll
    for (int r = 0; r < 8; r++) ar[r * 64 + lane] = f2bf(acc[r]);
    ar[512 + lane] = xb[(size_t)node * 64 + lane];   // self-loop block
  }
  __syncthreads();

  // (4) MFMA epilogue on waves 0-3; wave = col tile.
  if (wave < 4) {
    int q = lane >> 4;
    int m = lane & 15;
    float4v acc4 = {0.f, 0.f, 0.f, 0.f};
    const short8* Bp = (const short8*)Bf2;
    #pragma unroll
    for (int ks = 0; ks < 18; ks++) {
      short8 a = *(const short8*)(At + m * APITCH + ks * 32 + q * 8);
      short8 bfr = Bp[(ks * 4 + wave) * 64 + lane];
      acc4 = __builtin_amdgcn_mfma_f32_16x16x32_bf16(a, bfr, acc4, 0, 0, 0);
    }
    int c = wave * 16 + m;
    float bias = bsum[c];
    #pragma unroll
    for (int rr = 0; rr < 4; rr++) {
      out[(size_t)(nodeBase + q * 4 + rr) * 64 + c] = fmaxf(acc4[rr] + bias, 0.0f);
    }
  }
}

extern "C" void kernel_launch(void* const* d_in, const int* in_sizes, int n_in,
                              void* d_out, int out_size, void* d_ws, size_t ws_size,
                              hipStream_t stream) {
  const float* x     = (const float*)d_in[0];
  const int*   esrc  = (const int*)d_in[1];
  const int*   edst  = (const int*)d_in[2];
  const int*   erel  = (const int*)d_in[3];
  const float* ew    = (const float*)d_in[4];
  const float* Wlin  = (const float*)d_in[5];
  const float* blin  = (const float*)d_in[6];
  const float* Wself = (const float*)d_in[7];
  const float* bself = (const float*)d_in[8];
  float* out = (float*)d_out;

  char* ws = (char*)d_ws;
  size_t off = 0;
  auto alloc = [&](size_t bytes) -> void* {
    void* p = ws + off;
    off += (bytes + 255) & ~(size_t)255;
    return p;
  };
  int*            bucket_cursor = (int*)alloc((size_t)NBUCK * sizeof(int));           // zeroed in prep_cast
  uint2*          staged  = (uint2*)alloc((size_t)NBUCK * BCAP * sizeof(uint2));      // 9.2 MB
  unsigned short* Bf2     = (unsigned short*)alloc((size_t)18 * 4 * 64 * 8 * sizeof(unsigned short));
  float*          bsum    = (float*)alloc(64 * sizeof(float));
  unsigned short* xb      = (unsigned short*)alloc((size_t)NNODES * DIM * sizeof(unsigned short));  // 6.4 MB

  const int E4 = NEDGES / 4;
  prep_cast_kernel<<<CASTBLK + PREPBLK, 256, 0, stream>>>(Wlin, Wself, blin, bself,
                                                          (const float4*)x, Bf2, bsum,
                                                          (us4*)xb, bucket_cursor);
  binscatter_kernel<<<(E4 + 1023) / 1024, 1024, 0, stream>>>((const int4*)esrc, (const int4*)edst,
                                                             (const int4*)erel, (const float4*)ew,
                                                             bucket_cursor, staged, E4);
  fused_kernel<<<NBLK, 512, 0, stream>>>(bucket_cursor, staged, xb, Bf2, bsum, out);
}

// Round 13
// 161.939 us; speedup vs baseline: 1.0673x; 1.0673x over previous
//
#include <hip/hip_runtime.h>
#include <stdint.h>

// Problem constants (from reference)
#define NNODES 50000
#define NEDGES 1000000
#define DIM    64
#define NREL   8
#define NBUCK  391          // ceil(50000/128); bucket = dst >> 7 (128-node range)
#define BCAP   2944         // per-bucket record capacity (expected ~2558, +7.6 sigma)
#define NBIN   245          // binning blocks (1M edges / 4096)
#define CPITCH 392          // cntT/offT row pitch
#define NBLK   3125         // 50000 / 16 output blocks
#define APITCH 584          // LDS bf16 tile pitch (576 + 8)
#define PREPN  (18 * 4 * 64 * 8)

typedef __attribute__((ext_vector_type(8))) short short8;
typedef __attribute__((ext_vector_type(4))) float float4v;
typedef __attribute__((ext_vector_type(4))) unsigned short us4;

__device__ __forceinline__ float bf2f(unsigned short u) {
  return __uint_as_float(((unsigned int)u) << 16);
}
__device__ __forceinline__ unsigned short f2bf(float f) {
  unsigned int u = __float_as_uint(f);
  unsigned int r = (u + 0x7FFF + ((u >> 16) & 1)) >> 16;   // round-nearest-even
  return (unsigned short)r;
}

// K0: build. Prologue: x f32->bf16 cast + B-fragment prep + bias (grid-stride).
// Main: LDS counting sort of this block's 4096 edges by bucket, flush to the
// BLOCK-PRIVATE region staged2[j*4096..] (fully coalesced, no global atomics),
// and write per-(block,bucket) count/offset tables (coalesced rows).
// Record: x = src(16) | rel(3)<<16 | dst_low7(7)<<19, y = w bits.
__global__ __launch_bounds__(1024) void build_kernel(
    const float4* __restrict__ x4,
    const float* __restrict__ Wlin, const float* __restrict__ Wself,
    const float* __restrict__ blin, const float* __restrict__ bself,
    const int4* __restrict__ src4, const int4* __restrict__ dst4,
    const int4* __restrict__ rel4, const float4* __restrict__ w4,
    us4* __restrict__ xb, unsigned short* __restrict__ Bf2, float* __restrict__ bsum,
    uint2* __restrict__ staged2, int* __restrict__ cntT, int* __restrict__ offT,
    int E4) {
  __shared__ int lhist[NBUCK];
  __shared__ int lscan[NBUCK];
  __shared__ uint2 lrec[4096];              // 32 KB
  __shared__ unsigned short lbuck[4096];    // 8 KB
  int tid = threadIdx.x;
  int j = blockIdx.x;
  int gid = j * 1024 + tid;
  const int TOT = NBIN * 1024;

  // prologue: cast x (800K float4) + prep Bf2 + bsum
  for (int t = gid; t < NNODES * DIM / 4; t += TOT) {
    float4 v = x4[t];
    us4 o;
    o.x = f2bf(v.x); o.y = f2bf(v.y); o.z = f2bf(v.z); o.w = f2bf(v.w);
    xb[t] = o;
  }
  if (gid < PREPN) {
    int t = gid;
    int jj = t & 7;
    int l  = (t >> 3) & 63;
    int ct = (t >> 9) & 3;
    int ks = t >> 11;
    int k = ks * 32 + (l >> 4) * 8 + jj;
    int c = ct * 16 + (l & 15);
    float v = (k < 512) ? Wlin[(size_t)k * 64 + c] : Wself[(size_t)(k - 512) * 64 + c];
    Bf2[t] = f2bf(v);
  }
  if (gid < 64) bsum[gid] = blin[gid] + bself[gid];

  if (tid < NBUCK) lhist[tid] = 0;
  __syncthreads();
  bool valid = gid < E4;
  int4 s = {0,0,0,0}, d = {0,0,0,0}, r = {0,0,0,0};
  float4 w = {0.f,0.f,0.f,0.f};
  if (valid) { s = src4[gid]; d = dst4[gid]; r = rel4[gid]; w = w4[gid]; }
  int b0=0,b1=0,b2=0,b3=0,p0=0,p1=0,p2=0,p3=0;
  if (valid) {
    b0 = d.x >> 7; p0 = atomicAdd(&lhist[b0], 1);
    b1 = d.y >> 7; p1 = atomicAdd(&lhist[b1], 1);
    b2 = d.z >> 7; p2 = atomicAdd(&lhist[b2], 1);
    b3 = d.w >> 7; p3 = atomicAdd(&lhist[b3], 1);
  }
  __syncthreads();
  if (tid < 64) {                 // wave 0: exclusive scan of 391 counts
    int carry = 0;
    #pragma unroll
    for (int c = 0; c < 7; c++) {
      int i = c * 64 + tid;
      int v = (i < NBUCK) ? lhist[i] : 0;
      int inc = v;
      #pragma unroll
      for (int dd = 1; dd < 64; dd <<= 1) {
        int tt = __shfl_up(inc, dd);
        if (tid >= dd) inc += tt;
      }
      if (i < NBUCK) lscan[i] = carry + inc - v;
      carry += __shfl(inc, 63);
    }
  }
  __syncthreads();
  if (valid) {
    int q;
    q = lscan[b0] + p0; lrec[q] = make_uint2((unsigned)s.x | ((unsigned)r.x << 16) | ((unsigned)(d.x & 127) << 19), __float_as_uint(w.x));
    q = lscan[b1] + p1; lrec[q] = make_uint2((unsigned)s.y | ((unsigned)r.y << 16) | ((unsigned)(d.y & 127) << 19), __float_as_uint(w.y));
    q = lscan[b2] + p2; lrec[q] = make_uint2((unsigned)s.z | ((unsigned)r.z << 16) | ((unsigned)(d.z & 127) << 19), __float_as_uint(w.z));
    q = lscan[b3] + p3; lrec[q] = make_uint2((unsigned)s.w | ((unsigned)r.w << 16) | ((unsigned)(d.w & 127) << 19), __float_as_uint(w.w));
  }
  if (tid < NBUCK) {              // coalesced row write: this block's table column
    cntT[j * CPITCH + tid] = lhist[tid];
    offT[j * CPITCH + tid] = lscan[tid];
  }
  __syncthreads();
  int cntblk = NEDGES - j * 4096;
  if (cntblk > 4096) cntblk = 4096;
  uint2* myst = staged2 + (size_t)j * 4096;
  for (int i = tid; i < cntblk; i += 1024)   // PRIVATE, fully coalesced flush
    myst[i] = lrec[i];
}

// K1: per-bucket CSR build from private fragments. Wave 0 scans the 245
// per-block run lengths -> run bases; threads gather records via binary
// search (scattered READS); then 1024-key sort, degrees, coalesced meta
// write into the bucket's fixed region b*BCAP, roff2 per-bucket.
__global__ __launch_bounds__(1024) void csrbuild_kernel(
    const int* __restrict__ cntT, const int* __restrict__ offT,
    const uint2* __restrict__ staged2, uint2* __restrict__ meta,
    int* __restrict__ roff2) {
  __shared__ uint2 cache[BCAP];                 // 23.0 KB
  __shared__ short inv[BCAP];                   // 5.75 KB
  __shared__ int   hist[1024];
  __shared__ int   scn[1024];
  __shared__ int   ncur[1024];
  __shared__ float degf[1024];
  __shared__ int   runbase[257];
  __shared__ int   offs_l[256];
  __shared__ int   cnt_s;
  int b = blockIdx.x;
  int tid = threadIdx.x;
  if (tid < 1024) { hist[tid] = 0; degf[tid] = 0.f; }
  if (tid >= 64 && tid < 128) {   // wave 1: stage offT column
    for (int c = 0; c < 4; c++) {
      int jj = c * 64 + (tid - 64);
      if (jj < NBIN) offs_l[jj] = offT[jj * CPITCH + b];
    }
  }
  if (tid < 64) {                 // wave 0: scan 245 run lengths
    int carry = 0;
    #pragma unroll
    for (int c = 0; c < 4; c++) {
      int jj = c * 64 + tid;
      int v = (jj < NBIN) ? cntT[jj * CPITCH + b] : 0;
      int inc = v;
      #pragma unroll
      for (int dd = 1; dd < 64; dd <<= 1) {
        int tt = __shfl_up(inc, dd);
        if (tid >= dd) inc += tt;
      }
      if (c * 64 + tid < 257) runbase[jj] = carry + inc - v;
      carry += __shfl(inc, 63);
    }
    if (tid == 0) {
      runbase[NBIN] = carry;
      cnt_s = (carry < BCAP) ? carry : BCAP;
    }
  }
  __syncthreads();
  int cnt = cnt_s;

  // gather records (scattered run reads) + histogram
  for (int t = tid; t < cnt; t += 1024) {
    int lo = 0, hi = NBIN - 1;
    #pragma unroll
    for (int it = 0; it < 8; it++) {
      int mid = (lo + hi + 1) >> 1;
      bool g = runbase[mid] <= t;
      lo = g ? mid : lo;
      hi = g ? hi : (mid - 1);
    }
    int jj = lo;
    uint2 rec = staged2[(size_t)jj * 4096 + offs_l[jj] + (t - runbase[jj])];
    cache[t] = rec;
    int key = (((rec.x >> 19) & 127) << 3) | ((rec.x >> 16) & 7);
    atomicAdd(&hist[key], 1);
    atomicAdd(&degf[key], __uint_as_float(rec.y));
  }
  __syncthreads();
  if (tid < 64) {                 // wave 0: scan 1024 keys
    int carry = 0;
    #pragma unroll
    for (int c = 0; c < 16; c++) {
      int v = hist[c * 64 + tid];
      int inc = v;
      #pragma unroll
      for (int dd = 1; dd < 64; dd <<= 1) {
        int tt = __shfl_up(inc, dd);
        if (tid >= dd) inc += tt;
      }
      scn[c * 64 + tid]  = carry + inc - v;
      ncur[c * 64 + tid] = carry + inc - v;
      carry += __shfl(inc, 63);
    }
  }
  __syncthreads();
  if (tid < 1024) roff2[b * 1025 + tid] = b * BCAP + scn[tid];
  if (tid == 0)   roff2[b * 1025 + 1024] = b * BCAP + cnt;
  if (tid < 1024) {
    float d = degf[tid];
    degf[tid] = (d != 0.f) ? (1.0f / d) : 0.f;
  }
  __syncthreads();
  for (int i = tid; i < cnt; i += 1024) {        // pass A: rank -> inverse perm
    uint2 rec = cache[i];
    int key = (((rec.x >> 19) & 127) << 3) | ((rec.x >> 16) & 7);
    int pos = atomicAdd(&ncur[key], 1);
    inv[pos] = (short)i;
  }
  __syncthreads();
  for (int o = tid; o < cnt; o += 1024) {        // pass B: coalesced meta store
    int i = (int)inv[o];
    uint2 rec = cache[i];
    int key = (((rec.x >> 19) & 127) << 3) | ((rec.x >> 16) & 7);
    float sc = __uint_as_float(rec.y) * degf[key];
    meta[(size_t)b * BCAP + o] = make_uint2((rec.x & 0xFFFF) << 7, __float_as_uint(sc));
  }
}

// K2: FUSED aggregate + output GEMM (R11 engine). Block = 16 nodes, 512 threads.
// Phase 1: each wave aggregates 2 nodes (uniform s_load meta -> SGPR-base
// gather -> 1 fmac/edge). Phase 2: waves 0-3 MFMA, +bias, relu.
__global__ __launch_bounds__(512) void fused_kernel(const int* __restrict__ roff2,
                                                    const uint2* __restrict__ meta,
                                                    const unsigned short* __restrict__ xb,
                                                    const unsigned short* __restrict__ Bf2,
                                                    const float* __restrict__ bsum,
                                                    float* __restrict__ out) {
  __shared__ unsigned short At[16 * APITCH];   // 18.25 KB
  int tid  = threadIdx.x;
  int wave = tid >> 6;
  int lane = tid & 63;
  int nodeBase = blockIdx.x * 16;
  const char* xbb = (const char*)xb;
  int lane2 = lane * 2;

  #pragma unroll
  for (int i = 0; i < 2; i++) {
    int row  = wave * 2 + i;
    int node = __builtin_amdgcn_readfirstlane(nodeBase + row);
    int bb = node >> 7;
    int kk = (node & 127) * 8;
    int bnd = 0;
    if (lane < 9) bnd = roff2[bb * 1025 + kk + lane];

    int eb[9];
    #pragma unroll
    for (int k = 0; k < 9; k++) eb[k] = __builtin_amdgcn_readlane(bnd, k);  // SGPR bounds

    float acc[8];
    #pragma unroll
    for (int r = 0; r < 8; r++) acc[r] = 0.f;

    #pragma unroll
    for (int r = 0; r < 8; r++) {
      int e  = eb[r];
      int e1 = eb[r + 1];
      for (; e + 2 <= e1; e += 2) {
        uint2 m0 = meta[e];          // uniform -> s_load_dwordx2
        uint2 m1 = meta[e + 1];
        float v0 = bf2f(*(const unsigned short*)(xbb + m0.x + lane2));
        float v1 = bf2f(*(const unsigned short*)(xbb + m1.x + lane2));
        acc[r] += __uint_as_float(m0.y) * v0;
        acc[r] += __uint_as_float(m1.y) * v1;
      }
      if (e < e1) {
        uint2 m0 = meta[e];
        acc[r] += __uint_as_float(m0.y) * bf2f(*(const unsigned short*)(xbb + m0.x + lane2));
      }
    }
    unsigned short* ar = At + row * APITCH;
    #pragma unroll
    for (int r = 0; r < 8; r++) ar[r * 64 + lane] = f2bf(acc[r]);
    ar[512 + lane] = xb[(size_t)node * 64 + lane];   // self-loop block
  }
  __syncthreads();

  // Phase 2: MFMA on waves 0-3; wave = col tile.
  if (wave < 4) {
    int q = lane >> 4;
    int m = lane & 15;
    float4v acc4 = {0.f, 0.f, 0.f, 0.f};
    const short8* Bp = (const short8*)Bf2;
    #pragma unroll
    for (int ks = 0; ks < 18; ks++) {
      short8 a = *(const short8*)(At + m * APITCH + ks * 32 + q * 8);
      short8 bfr = Bp[(ks * 4 + wave) * 64 + lane];
      acc4 = __builtin_amdgcn_mfma_f32_16x16x32_bf16(a, bfr, acc4, 0, 0, 0);
    }
    int c = wave * 16 + m;
    float bias = bsum[c];
    #pragma unroll
    for (int rr = 0; rr < 4; rr++) {
      out[(size_t)(nodeBase + q * 4 + rr) * 64 + c] = fmaxf(acc4[rr] + bias, 0.0f);
    }
  }
}

extern "C" void kernel_launch(void* const* d_in, const int* in_sizes, int n_in,
                              void* d_out, int out_size, void* d_ws, size_t ws_size,
                              hipStream_t stream) {
  const float* x     = (const float*)d_in[0];
  const int*   esrc  = (const int*)d_in[1];
  const int*   edst  = (const int*)d_in[2];
  const int*   erel  = (const int*)d_in[3];
  const float* ew    = (const float*)d_in[4];
  const float* Wlin  = (const float*)d_in[5];
  const float* blin  = (const float*)d_in[6];
  const float* Wself = (const float*)d_in[7];
  const float* bself = (const float*)d_in[8];
  float* out = (float*)d_out;

  char* ws = (char*)d_ws;
  size_t off = 0;
  auto alloc = [&](size_t bytes) -> void* {
    void* p = ws + off;
    off += (bytes + 255) & ~(size_t)255;
    return p;
  };
  uint2*          staged2 = (uint2*)alloc((size_t)NBIN * 4096 * sizeof(uint2));       // 8.0 MB
  int*            cntT    = (int*)alloc((size_t)NBIN * CPITCH * sizeof(int));         // 0.38 MB
  int*            offT    = (int*)alloc((size_t)NBIN * CPITCH * sizeof(int));         // 0.38 MB
  uint2*          meta    = (uint2*)alloc((size_t)NBUCK * BCAP * sizeof(uint2));      // 9.2 MB
  int*            roff2   = (int*)alloc((size_t)NBUCK * 1025 * sizeof(int));          // 1.6 MB
  unsigned short* Bf2     = (unsigned short*)alloc((size_t)PREPN * sizeof(unsigned short));
  float*          bsum    = (float*)alloc(64 * sizeof(float));
  unsigned short* xb      = (unsigned short*)alloc((size_t)NNODES * DIM * sizeof(unsigned short));  // 6.4 MB

  const int E4 = NEDGES / 4;
  build_kernel<<<NBIN, 1024, 0, stream>>>((const float4*)x, Wlin, Wself, blin, bself,
                                          (const int4*)esrc, (const int4*)edst,
                                          (const int4*)erel, (const float4*)ew,
                                          (us4*)xb, Bf2, bsum, staged2, cntT, offT, E4);
  csrbuild_kernel<<<NBUCK, 1024, 0, stream>>>(cntT, offT, staged2, meta, roff2);
  fused_kernel<<<NBLK, 512, 0, stream>>>(roff2, meta, xb, Bf2, bsum, out);
}